// Round 6
// baseline (242.468 us; speedup 1.0000x reference)
//
#include <hip/hip_runtime.h>

typedef short bf16x8 __attribute__((ext_vector_type(8)));
typedef float f32x4 __attribute__((ext_vector_type(4)));
typedef unsigned short u16;

#define S_LEN 4096
#define D_DIM 256
#define NROW  16384   // B*S

__device__ __forceinline__ u16 f2bf(float f) {
    union { float f; unsigned u; } v; v.f = f;
    unsigned r = v.u + 0x7FFFu + ((v.u >> 16) & 1u);
    return (u16)(r >> 16);
}

// Fragment-linear layouts (bf16):
//  Q/K/W: row-tile t (16 rows), kk (32-k chunk): frag = t*4096 + kk*512,
//         elem(row_local, col) at ((col>>3)&3)*128 + row_local*8 + (col&7).
//         Lane l reads frag + l*8 -> row=l&15, k=(l>>4)*8+e. 1KB coalesced.
//  V^T:   panel p = b*64+kt (64 keys x 256 d = 32KB): frag(dtile,kk2) =
//         p*16384 + (dtile*2+kk2)*512.
//  A 64-row K/Q panel (4 tiles) is 32KB CONTIGUOUS: frag f=cf*8+kk at
//  panel_base + f*512.
__device__ __forceinline__ size_t fr_qk(int t, int kk) {
    return (size_t)t * 4096 + kk * 512;
}
__device__ __forceinline__ size_t fr_v(int p, int dt, int kk2) {
    return (size_t)p * 16384 + (dt * 2 + kk2) * 512;
}

// async global->LDS, 16B/lane: lane l's 16B from g+l*8(u16) lands at lds+l*16.
__device__ __forceinline__ void gll16(const u16* g, u16* l) {
    __builtin_amdgcn_global_load_lds(
        (const __attribute__((address_space(1))) unsigned int*)g,
        (__attribute__((address_space(3))) unsigned int*)l, 16, 0, 0);
}

// ---------------- Kernel W: W f32 -> bf16 fragments -----------------------
__global__ __launch_bounds__(256) void wconv(
    const float* __restrict__ Wq, const float* __restrict__ Wk,
    const float* __restrict__ Wv, u16* __restrict__ Wf)
{
    int i = blockIdx.x * 256 + threadIdx.x;   // 24576 threads
    int m = i >> 13;
    int idx = i & 8191;
    int ocol = idx >> 5;                      // 0..255 (row of W = out col)
    int d0 = (idx & 31) * 8;
    const float* s = (m == 0 ? Wq : (m == 1 ? Wk : Wv)) + ocol * 256 + d0;
    float4 v0 = *reinterpret_cast<const float4*>(s);
    float4 v1 = *reinterpret_cast<const float4*>(s + 4);
    union { ushort4 h[2]; int4 q; } t;
    t.h[0] = make_ushort4(f2bf(v0.x), f2bf(v0.y), f2bf(v0.z), f2bf(v0.w));
    t.h[1] = make_ushort4(f2bf(v1.x), f2bf(v1.y), f2bf(v1.z), f2bf(v1.w));
    size_t off = (size_t)m * 65536 + fr_qk(ocol >> 4, d0 >> 5)
               + ((d0 >> 3) & 3) * 128 + (ocol & 15) * 8;
    *reinterpret_cast<int4*>(Wf + off) = t.q;
}

// ---------------- Kernel A: QKV projection (32 rows/block) ----------------
__global__ __launch_bounds__(256) void qkv_proj(
    const float* __restrict__ x, const u16* __restrict__ Wf,
    const float* __restrict__ bq, const float* __restrict__ bk,
    const float* __restrict__ bv,
    u16* __restrict__ Qf, u16* __restrict__ Kf, u16* __restrict__ Vf)
{
    __shared__ u16 xs[32][264];
    const int tid = threadIdx.x;
    const int r0 = blockIdx.x * 32;

    #pragma unroll
    for (int i = 0; i < 8; ++i) {
        int c = i * 256 + tid;               // 2048 float4 chunks
        int row = c >> 6, c4 = c & 63;
        float4 v = reinterpret_cast<const float4*>(x + (size_t)(r0 + row) * D_DIM)[c4];
        *reinterpret_cast<ushort4*>(&xs[row][c4 * 4]) =
            make_ushort4(f2bf(v.x), f2bf(v.y), f2bf(v.z), f2bf(v.w));
    }
    __syncthreads();

    const int w = tid >> 6, l = tid & 63, lr = l & 15, lg = l >> 4;
    const int c0 = w * 64;

    bf16x8 a[2][8];
    #pragma unroll
    for (int qs = 0; qs < 2; ++qs)
        #pragma unroll
        for (int kk = 0; kk < 8; ++kk)
            a[qs][kk] = *reinterpret_cast<const bf16x8*>(&xs[qs * 16 + lr][kk * 32 + lg * 8]);

    const float* Bs[3] = {bq, bk, bv};

    #pragma unroll
    for (int m = 0; m < 3; ++m) {
        const u16* Wm = Wf + (size_t)m * 65536;
        f32x4 acc[2][4] = {};
        #pragma unroll
        for (int kk = 0; kk < 8; ++kk) {
            #pragma unroll
            for (int cf = 0; cf < 4; ++cf) {
                bf16x8 wfr = *reinterpret_cast<const bf16x8*>(
                    Wm + fr_qk(w * 4 + cf, kk) + l * 8);
                acc[0][cf] = __builtin_amdgcn_mfma_f32_16x16x32_bf16(a[0][kk], wfr, acc[0][cf], 0, 0, 0);
                acc[1][cf] = __builtin_amdgcn_mfma_f32_16x16x32_bf16(a[1][kk], wfr, acc[1][cf], 0, 0, 0);
            }
        }
        if (m < 2) {
            u16* outp = (m == 0) ? Qf : Kf;
            int t = r0 >> 4;
            #pragma unroll
            for (int qs = 0; qs < 2; ++qs) {
                #pragma unroll
                for (int cf = 0; cf < 4; ++cf) {
                    int col = c0 + cf * 16 + lr;
                    float bias = Bs[m][col];
                    size_t base = fr_qk(t + qs, col >> 5) + ((col >> 3) & 3) * 128 + (col & 7);
                    #pragma unroll
                    for (int r = 0; r < 4; ++r)
                        outp[base + (lg * 4 + r) * 8] = f2bf(acc[qs][cf][r] + bias);
                }
            }
        } else {
            int p  = (r0 >> 12) * 64 + ((r0 & 4095) >> 6);
            int kb = r0 & 63;
            #pragma unroll
            for (int qs = 0; qs < 2; ++qs) {
                #pragma unroll
                for (int cf = 0; cf < 4; ++cf) {
                    int d = c0 + cf * 16 + lr;
                    float bias = bv[d];
                    #pragma unroll
                    for (int r = 0; r < 4; ++r) {
                        int key = kb + qs * 16 + lg * 4 + r;
                        size_t off = fr_v(p, d >> 4, key >> 5)
                                   + ((key >> 3) & 3) * 128 + (d & 15) * 8 + (key & 7);
                        Vf[off] = f2bf(acc[qs][cf][r] + bias);
                    }
                }
            }
        }
    }
}

// ---------------- Kernel B: partial column-softmax denominators -----------
// Zb[b,k] += sum over half the queries of exp(s[b,q,k]/16).
// Block = 128 keys (wave w holds 32 in regs) x one q-half; grid 256.
// Exactly 2 atomic contributions per key -> bit-deterministic.
__global__ __launch_bounds__(256) void col_denom(
    const u16* __restrict__ Qf, const u16* __restrict__ Kf, float* __restrict__ Zb)
{
    __shared__ __align__(16) u16 Qls[2][16384];   // 2 x 32KB q-panels
    const int tid = threadIdx.x, blk = blockIdx.x;
    const int g = blk & 7;
    const int b = g >> 1, qhalf = g & 1;          // XCD-clustered (b,qhalf)
    const int kt = blk >> 3;                      // key-tile 0..31 (128 keys)
    const int w = tid >> 6, l = tid & 63, lr = l & 15, lg = l >> 4;
    const int k0 = kt * 128;
    const int base_tq = b * 256;                  // (b*S_LEN)/16

    bf16x8 kreg[2][8];
    #pragma unroll
    for (int ks = 0; ks < 2; ++ks) {
        const int tkw = base_tq + ((k0 + w * 32 + ks * 16) >> 4);
        #pragma unroll
        for (int kk = 0; kk < 8; ++kk)
            kreg[ks][kk] = *reinterpret_cast<const bf16x8*>(Kf + fr_qk(tkw, kk) + l * 8);
    }

    #define STAGE_Q(qp, nb) do { \
        const u16* g_ = Qf + ((size_t)(base_tq + (qp) * 4)) * 4096 + (w * 8) * 512 + l * 8; \
        u16* d_ = &Qls[nb][(w * 8) * 512]; \
        _Pragma("unroll") \
        for (int f_ = 0; f_ < 8; ++f_) gll16(g_ + f_ * 512, d_ + f_ * 512); \
    } while (0)

    STAGE_Q(qhalf * 32, 0);
    __syncthreads();

    float Z[2][4] = {};
    const float SC = 0.0625f;

    for (int it = 0; it < 32; ++it) {
        const int cur = it & 1;
        if (it < 31) STAGE_Q(qhalf * 32 + it + 1, cur ^ 1);

        f32x4 acc[2][4] = {};
        #pragma unroll
        for (int kk = 0; kk < 8; ++kk) {
            #pragma unroll
            for (int cf = 0; cf < 4; ++cf) {
                bf16x8 qfr = *reinterpret_cast<const bf16x8*>(
                    &Qls[cur][(cf * 8 + kk) * 512 + l * 8]);
                acc[0][cf] = __builtin_amdgcn_mfma_f32_16x16x32_bf16(kreg[0][kk], qfr, acc[0][cf], 0, 0, 0);
                acc[1][cf] = __builtin_amdgcn_mfma_f32_16x16x32_bf16(kreg[1][kk], qfr, acc[1][cf], 0, 0, 0);
            }
        }
        #pragma unroll
        for (int ks = 0; ks < 2; ++ks)
            #pragma unroll
            for (int cf = 0; cf < 4; ++cf)
                #pragma unroll
                for (int r = 0; r < 4; ++r)
                    Z[ks][r] += __expf(acc[ks][cf][r] * SC);
        __syncthreads();
    }

    #pragma unroll
    for (int ks = 0; ks < 2; ++ks) {
        #pragma unroll
        for (int r = 0; r < 4; ++r) {
            float z = Z[ks][r];
            z += __shfl_xor(z, 1);
            z += __shfl_xor(z, 2);
            z += __shfl_xor(z, 4);
            z += __shfl_xor(z, 8);
            if (lr == 0)
                unsafeAtomicAdd(&Zb[b * S_LEN + k0 + w * 32 + ks * 16 + lg * 4 + r], z);
        }
    }
    #undef STAGE_Q
}

// ---------------- Kernel C: out += (exp(S)/Z) @ V (key-half) --------------
// Block = 128 q rows (wave w owns 2x16) x one key-half (32 panels).
// Every K/V fragment read feeds 2 MFMAs. 2 atomic adds per out element.
__global__ __launch_bounds__(256, 1) void attn_out(
    const u16* __restrict__ Qf, const u16* __restrict__ Kf, const u16* __restrict__ Vf,
    const float* __restrict__ Zb, float* __restrict__ out)
{
    __shared__ __align__(16) u16 Kls[2][16384];   // 2 x 32KB K panels
    __shared__ __align__(16) u16 Vls[2][16384];   // 2 x 32KB V^T panels
    __shared__ __align__(16) u16 ps[4][2304];     // per-wave P tile [32][72]

    const int tid = threadIdx.x, blk = blockIdx.x;
    const int g = blk & 7;
    const int b = g >> 1, khalf = g & 1;          // XCD-clustered (b,khalf)
    const int qt = blk >> 3;                      // q-tile 0..31 (128 rows)
    const int w = tid >> 6, l = tid & 63, lr = l & 15, lg = l >> 4;
    const int qb = qt * 128;
    const int base_tk = b * 256;                  // (b*S_LEN)/16

    bf16x8 qreg[2][8];
    #pragma unroll
    for (int qs = 0; qs < 2; ++qs) {
        const int tq = base_tk + ((qb + qs * 64 + w * 16) >> 4);
        #pragma unroll
        for (int kk = 0; kk < 8; ++kk)
            qreg[qs][kk] = *reinterpret_cast<const bf16x8*>(Qf + fr_qk(tq, kk) + l * 8);
    }

    // wave 0,1 stage K panel halves; wave 2,3 stage V panel halves.
    #define STAGE_KV(kt_, nb) do { \
        if (w < 2) { \
            const u16* g_ = Kf + ((size_t)(base_tk + (kt_) * 4)) * 4096 + (w * 16) * 512 + l * 8; \
            u16* d_ = &Kls[nb][(w * 16) * 512]; \
            _Pragma("unroll") \
            for (int f_ = 0; f_ < 16; ++f_) gll16(g_ + f_ * 512, d_ + f_ * 512); \
        } else { \
            const u16* g_ = Vf + ((size_t)(b * 64 + (kt_))) * 16384 + ((w - 2) * 16) * 512 + l * 8; \
            u16* d_ = &Vls[nb][((w - 2) * 16) * 512]; \
            _Pragma("unroll") \
            for (int f_ = 0; f_ < 16; ++f_) gll16(g_ + f_ * 512, d_ + f_ * 512); \
        } \
    } while (0)

    STAGE_KV(khalf * 32, 0);
    __syncthreads();

    f32x4 oacc[2][16] = {};
    const float SC = 0.0625f;

    for (int it = 0; it < 32; ++it) {
        const int kt = khalf * 32 + it;
        const int cur = it & 1;
        if (it < 31) STAGE_KV(kt + 1, cur ^ 1);

        float Lv[4];
        #pragma unroll
        for (int cf = 0; cf < 4; ++cf)
            Lv[cf] = logf(Zb[b * S_LEN + kt * 64 + cf * 16 + lr]);

        // QK^T from staged K: 32 fragment reads -> 64 MFMAs
        f32x4 sacc[2][4] = {};
        #pragma unroll
        for (int kk = 0; kk < 8; ++kk) {
            #pragma unroll
            for (int cf = 0; cf < 4; ++cf) {
                bf16x8 kfr = *reinterpret_cast<const bf16x8*>(
                    &Kls[cur][(cf * 8 + kk) * 512 + l * 8]);
                sacc[0][cf] = __builtin_amdgcn_mfma_f32_16x16x32_bf16(qreg[0][kk], kfr, sacc[0][cf], 0, 0, 0);
                sacc[1][cf] = __builtin_amdgcn_mfma_f32_16x16x32_bf16(qreg[1][kk], kfr, sacc[1][cf], 0, 0, 0);
            }
        }
        // P = exp(s/16 - log Z) -> per-wave LDS (A-operand layout)
        #pragma unroll
        for (int cf = 0; cf < 4; ++cf) {
            #pragma unroll
            for (int qs = 0; qs < 2; ++qs) {
                #pragma unroll
                for (int r = 0; r < 4; ++r) {
                    float p = __expf(fmaf(sacc[qs][cf][r], SC, -Lv[cf]));
                    ps[w][(qs * 16 + lg * 4 + r) * 72 + cf * 16 + lr] = f2bf(p);
                }
            }
        }
        // PV from staged V^T: 32 fragment reads -> 64 MFMAs
        #pragma unroll
        for (int kk2 = 0; kk2 < 2; ++kk2) {
            bf16x8 af0 = *reinterpret_cast<const bf16x8*>(&ps[w][lr * 72 + kk2 * 32 + lg * 8]);
            bf16x8 af1 = *reinterpret_cast<const bf16x8*>(&ps[w][(16 + lr) * 72 + kk2 * 32 + lg * 8]);
            #pragma unroll
            for (int cf2 = 0; cf2 < 16; ++cf2) {
                bf16x8 vfr = *reinterpret_cast<const bf16x8*>(
                    &Vls[cur][(cf2 * 2 + kk2) * 512 + l * 8]);
                oacc[0][cf2] = __builtin_amdgcn_mfma_f32_16x16x32_bf16(af0, vfr, oacc[0][cf2], 0, 0, 0);
                oacc[1][cf2] = __builtin_amdgcn_mfma_f32_16x16x32_bf16(af1, vfr, oacc[1][cf2], 0, 0, 0);
            }
        }
        __syncthreads();
    }

    // epilogue: 2 deterministic atomic contributions per out element
    #pragma unroll
    for (int qs = 0; qs < 2; ++qs) {
        #pragma unroll
        for (int cf2 = 0; cf2 < 16; ++cf2) {
            #pragma unroll
            for (int r = 0; r < 4; ++r) {
                int row = qb + qs * 64 + w * 16 + lg * 4 + r;
                unsafeAtomicAdd(&out[((size_t)(b * S_LEN + row)) * D_DIM + cf2 * 16 + lr],
                                oacc[qs][cf2][r]);
            }
        }
    }
    #undef STAGE_KV
}

// ---------------- launcher ------------------------------------------------
extern "C" void kernel_launch(void* const* d_in, const int* in_sizes, int n_in,
                              void* d_out, int out_size, void* d_ws, size_t ws_size,
                              hipStream_t stream) {
    const float* x  = (const float*)d_in[0];
    const float* Wq = (const float*)d_in[1];
    const float* bq = (const float*)d_in[2];
    const float* Wk = (const float*)d_in[3];
    const float* bk = (const float*)d_in[4];
    const float* Wv = (const float*)d_in[5];
    const float* bv = (const float*)d_in[6];
    float* out = (float*)d_out;

    u16* Qf = (u16*)d_ws;                            // 8 MB (fragment layout)
    u16* Kf = Qf + (size_t)NROW * D_DIM;             // 8 MB
    u16* Vf = Kf + (size_t)NROW * D_DIM;             // 8 MB
    float* Zb = (float*)(Vf + (size_t)NROW * D_DIM); // 64 KB (raw col sums)
    u16* Wf = (u16*)(Zb + NROW);                     // 384 KB

    hipMemsetAsync(out, 0, (size_t)NROW * D_DIM * sizeof(float), stream);
    hipMemsetAsync(Zb, 0, (size_t)NROW * sizeof(float), stream);

    wconv<<<96, 256, 0, stream>>>(Wq, Wk, Wv, Wf);
    qkv_proj<<<NROW / 32, 256, 0, stream>>>(x, Wf, bq, bk, bv, Qf, Kf, Vf);
    col_denom<<<256, 256, 0, stream>>>(Qf, Kf, Zb);
    attn_out<<<256, 256, 0, stream>>>(Qf, Kf, Vf, Zb, out);
}